// Round 15
// baseline (149.940 us; speedup 1.0000x reference)
//
#include <hip/hip_runtime.h>
#include <hip/hip_bf16.h>

#define N_NODES 50000
#define N_EDGES 800000
#define NBUK 196          // buckets of 256 dst nodes
#define NBLK 196          // edge-chunk blocks: 196*4096 >= E
#define EPB  4096
#define PREP_NB 220
#define GD 782            // 782*4 wave-tiles >= 3125
#define SUBCAP 4608

typedef __attribute__((ext_vector_type(8))) short bf16x8;
typedef __attribute__((ext_vector_type(4))) float f32x4;

__device__ __forceinline__ unsigned short f2b(float f) {
    unsigned u = __float_as_uint(f);
    return (unsigned short)((u + 0x7FFF + ((u >> 16) & 1)) >> 16);
}
__device__ __forceinline__ float b2f(unsigned short b) {
    return __uint_as_float(((unsigned)b) << 16);
}

// in-block exclusive scan of btot[NBUK] -> seb[NBUK+1] (both args LDS except btot)
__device__ __forceinline__ void scan_btot(const int* __restrict__ btot,
                                          int* seb, int* wsum, int t) {
    int v = (t < NBUK) ? btot[t] : 0;
    int lane = t & 63, wid = t >> 6;
    int incl = v;
    #pragma unroll
    for (int d = 1; d < 64; d <<= 1) {
        int u = __shfl_up(incl, d);
        if (lane >= d) incl += u;
    }
    if (lane == 63) wsum[wid] = incl;
    __syncthreads();
    int woff = 0;
    for (int w = 0; w < wid; ++w) woff += wsum[w];
    if (t < NBUK) seb[t] = incl - v + woff;
    if (t == 255) seb[NBUK] = incl + woff;    // == N_EDGES
    __syncthreads();
}

// ---------------- CSR build (two-level bucket sort) ----------------

// 1) per-(block,bucket) counts TRANSPOSED; blocks >= NBLK do weight prep
__global__ __launch_bounds__(256) void k_cnt(
    const int* __restrict__ dst, int* __restrict__ cntM,
    const float* __restrict__ W11, const float* __restrict__ Wc1,
    const float* __restrict__ W12, const float* __restrict__ W13,
    const float* __restrict__ W21, const float* __restrict__ Wc2,
    const float* __restrict__ W22, const float* __restrict__ W23,
    const float* __restrict__ Wf,
    unsigned short* __restrict__ B1, unsigned short* __restrict__ B2,
    unsigned short* __restrict__ Bc) {
    int t = threadIdx.x, blk = blockIdx.x;
    if (blk >= NBLK) {
        // frag layout: B[((nt*KS+ks)*64+lane)*8+i] = W(k=ks*32+(lane>>4)*8+i, col=nt*16+(lane&15))
        int idx = (blk - NBLK) * 256 + t;
        if (idx < 10240) {                       // B1: KS=2, K=64, 160 cols
            int i = idx & 7, l = (idx >> 3) & 63, ks = (idx >> 9) & 1, nt = idx >> 10;
            int k = ks * 32 + ((l >> 4) << 3) + i;
            int col = nt * 16 + (l & 15);
            float w = (col < 64) ? W11[k * 64 + col]
                    : (col < 128) ? Wc1[k * 64 + col - 64]
                    : (col < 144) ? W12[k * 16 + col - 128]
                                  : W13[k * 16 + col - 144];
            B1[idx] = f2b(w);
        } else if (idx < 10240 + 25600) {        // B2: KS=5, K=144, 160 cols
            int j = idx - 10240;
            int i = j & 7, l = (j >> 3) & 63;
            int ks = (j >> 9) % 5, nt = j / 2560;
            int k = ks * 32 + ((l >> 4) << 3) + i;
            int col = nt * 16 + (l & 15);
            float w = 0.f;
            if (k < 144)
                w = (col < 64) ? W21[k * 64 + col]
                  : (col < 128) ? Wc2[k * 64 + col - 64]
                  : (col < 144) ? W22[k * 16 + col - 128]
                                : W23[k * 16 + col - 144];
            B2[j] = f2b(w);
        } else if (idx < 10240 + 25600 + 20480) { // Bc: KS=5, K=144, 128 cols
            int j = idx - 10240 - 25600;
            int i = j & 7, l = (j >> 3) & 63;
            int ks = (j >> 9) % 5, nt = j / 2560;
            int k = ks * 32 + ((l >> 4) << 3) + i;
            int col = nt * 16 + (l & 15);
            Bc[j] = (k < 144) ? f2b(Wf[k * 128 + col]) : (unsigned short)0;
        }
        return;
    }
    __shared__ int cl[NBUK];
    for (int i = t; i < NBUK; i += 256) cl[i] = 0;
    __syncthreads();
    int e0 = blk * EPB;
    #pragma unroll
    for (int r = 0; r < EPB / 256; ++r) {
        int e = e0 + r * 256 + t;
        if (e < N_EDGES) atomicAdd(&cl[dst[e] >> 8], 1);
    }
    __syncthreads();
    for (int i = t; i < NBUK; i += 256) cntM[i * NBLK + blk] = cl[i];
}

// 2) per-bucket scan over blocks (wave per bucket); bucket totals -> btot
__global__ __launch_bounds__(256) void k_colA(int* __restrict__ cntM,
                                              int* __restrict__ btot) {
    int t = threadIdx.x;
    int k = blockIdx.x * 4 + (t >> 6);
    int lane = t & 63;
    int* row = cntM + k * NBLK;
    int4 v = {0, 0, 0, 0};
    if (lane < 49) v = *(const int4*)&row[lane * 4];
    int s = v.x + v.y + v.z + v.w;
    int incl = s;
    #pragma unroll
    for (int d = 1; d < 64; d <<= 1) {
        int u = __shfl_up(incl, d);
        if (lane >= d) incl += u;
    }
    int excl = incl - s;
    if (lane < 49) {
        int4 o;
        o.x = excl;
        o.y = excl + v.x;
        o.z = excl + v.x + v.y;
        o.w = excl + v.x + v.y + v.z;
        *(int4*)&row[lane * 4] = o;
    }
    if (lane == 63) btot[k] = incl;
}

// ---------------- MFMA dense layer-1 body (K=64) ----------------
// D-frag (verified m89/m91): col=lane&15, row=(lane>>4)*4+reg.
__device__ __forceinline__ void dense1_body(
    int tile, int ln, const float* __restrict__ xf,
    const unsigned short* __restrict__ B1,
    const float* __restrict__ b11, const float* __restrict__ b12,
    const float* __restrict__ b13,
    unsigned short* __restrict__ hb80, unsigned short* __restrict__ xwA) {
    if (tile >= 3125) return;
    int c = ln & 15, g = ln >> 4;
    int arow = tile * 16 + c;
    float bia[4];
    #pragma unroll
    for (int j = 0; j < 4; ++j) bia[j] = b11[j * 16 + c];
    float b8 = b12[c], b9 = b13[c];
    f32x4 acc[10];
    #pragma unroll
    for (int nt = 0; nt < 10; ++nt) acc[nt] = f32x4{0.f, 0.f, 0.f, 0.f};
    const bf16x8* bfrag = (const bf16x8*)(B1 + (size_t)ln * 8);
    #pragma unroll
    for (int ks = 0; ks < 2; ++ks) {
        int kb = ks * 32 + g * 8;
        const float* rp = xf + (size_t)arow * 64 + kb;
        float4 q0 = *(const float4*)rp;
        float4 q1 = *(const float4*)(rp + 4);
        union { bf16x8 v; unsigned short u[8]; } af;
        af.u[0] = f2b(q0.x); af.u[1] = f2b(q0.y); af.u[2] = f2b(q0.z); af.u[3] = f2b(q0.w);
        af.u[4] = f2b(q1.x); af.u[5] = f2b(q1.y); af.u[6] = f2b(q1.z); af.u[7] = f2b(q1.w);
        #pragma unroll
        for (int nt = 0; nt < 10; ++nt) {
            bf16x8 b = bfrag[(nt * 2 + ks) * 64];
            acc[nt] = __builtin_amdgcn_mfma_f32_16x16x32_bf16(af.v, b, acc[nt], 0, 0, 0);
        }
    }
    #pragma unroll
    for (int r = 0; r < 4; ++r) {
        int orow = tile * 16 + g * 4 + r;
        size_t hbase = (size_t)orow * 80;
        #pragma unroll
        for (int nt = 0; nt < 4; ++nt)
            hb80[hbase + nt * 16 + c] = f2b(fmaxf(acc[nt][r] + bia[nt], 0.f));
        #pragma unroll
        for (int nt = 4; nt < 8; ++nt)
            xwA[(size_t)orow * 64 + (nt - 4) * 16 + c] = f2b(acc[nt][r]);
        float p = fmaxf(acc[8][r] + b8, 0.f) * fmaxf(acc[9][r] + b9, 0.f);
        hb80[hbase + 64 + c] = f2b(p);
    }
}

// 3) MERGED: blocks [0,NBLK) bucketize (ebase derived in-block from btot);
//    blocks [NBLK,NBLK+GD) run dense layer-1.
__global__ __launch_bounds__(256) void k_bd1(
    const int* __restrict__ src, const int* __restrict__ dst,
    const float* __restrict__ ea, const int* __restrict__ cntM,
    const int* __restrict__ btot, uint2* __restrict__ ebuf,
    const float* __restrict__ xf, const unsigned short* __restrict__ B1,
    const float* __restrict__ b11, const float* __restrict__ b12,
    const float* __restrict__ b13,
    unsigned short* __restrict__ hb80, unsigned short* __restrict__ xwA) {
    int t = threadIdx.x, blk = blockIdx.x;
    if (blk >= NBLK) {
        int tile = (blk - NBLK) * 4 + (t >> 6);
        dense1_body(tile, t & 63, xf, B1, b11, b12, b13, hb80, xwA);
        return;
    }
    __shared__ int seb[NBUK + 1];
    __shared__ int wsum[4];
    __shared__ int base[NBUK];
    __shared__ int run[NBUK];
    scan_btot(btot, seb, wsum, t);
    if (t < NBUK) { base[t] = seb[t] + cntM[t * NBLK + blk]; run[t] = 0; }
    __syncthreads();
    int e0 = blk * EPB;
    #pragma unroll
    for (int r = 0; r < EPB / 256; ++r) {
        int e = e0 + r * 256 + t;
        if (e < N_EDGES) {
            int d = dst[e];
            int bk = d >> 8;
            int pos = atomicAdd(&run[bk], 1);
            ebuf[base[bk] + pos] =
                make_uint2((((unsigned)f2b(ea[e])) << 16) | (unsigned)src[e],
                           (unsigned)(d & 255));
        }
    }
}

// 4) per-bucket: LDS-cached edges; deg+scan -> off[]; dst-sorted epack
__global__ __launch_bounds__(256) void k_sub(
    const uint2* __restrict__ ebuf, const int* __restrict__ btot,
    unsigned* __restrict__ epack, int* __restrict__ off) {
    __shared__ uint2 ebl[SUBCAP];
    __shared__ int seb[NBUK + 1];
    __shared__ int deg[256], lofs[256], cnt[256];
    __shared__ int wsum[4];
    int t = threadIdx.x, b = blockIdx.x;
    scan_btot(btot, seb, wsum, t);
    deg[t] = 0; cnt[t] = 0;
    __syncthreads();
    int s = seb[b], e = seb[b + 1];
    int n = e - s;
    bool lds = (n <= SUBCAP);
    if (lds) {
        for (int i = t; i < n; i += 256) {
            uint2 u = ebuf[s + i];
            ebl[i] = u;
            atomicAdd(&deg[u.y], 1);
        }
    } else {
        for (int i = s + t; i < e; i += 256) atomicAdd(&deg[ebuf[i].y], 1);
    }
    __syncthreads();
    int v = deg[t];
    int lane = t & 63, wid = t >> 6;
    int incl = v;
    #pragma unroll
    for (int d = 1; d < 64; d <<= 1) {
        int u = __shfl_up(incl, d);
        if (lane >= d) incl += u;
    }
    if (lane == 63) wsum[wid] = incl;
    __syncthreads();
    int woff = 0;
    for (int w = 0; w < wid; ++w) woff += wsum[w];
    lofs[t] = incl - v + woff;
    __syncthreads();
    int gd = b * 256 + t;
    if (gd < N_NODES) off[gd] = s + lofs[t];
    if (b == NBUK - 1 && t == 0) off[N_NODES] = N_EDGES;
    if (lds) {
        for (int i = t; i < n; i += 256) {
            uint2 u = ebl[i];
            int pos = atomicAdd(&cnt[u.y], 1);
            epack[s + lofs[u.y] + pos] = u.x;
        }
    } else {
        for (int i = s + t; i < e; i += 256) {
            uint2 u = ebuf[i];
            int pos = atomicAdd(&cnt[u.y], 1);
            epack[s + lofs[u.y] + pos] = u.x;
        }
    }
}

// ---------------- fused tile aggregation (wave-local, into LDS) ----------------
// 2 nodes concurrent per wave (half h), 4 octets x 8 lanes x uint4 per edge.
// Writes relu(agg + bc) bf16 rows [wv*16 .. +16) x 64 cols into aggL (pad 72).
__device__ __forceinline__ void agg_tile(
    int tile, int wv, int ln,
    const int* __restrict__ off, const unsigned* __restrict__ epack,
    const unsigned short* __restrict__ xw, const float* __restrict__ bc,
    unsigned short* aggL) {
    const uint4* xw128 = (const uint4*)xw;
    int h = ln >> 5, q2 = (ln >> 3) & 3, c8 = ln & 7;
    float4 bv0 = *(const float4*)&bc[8 * c8];
    float4 bv1 = *(const float4*)&bc[8 * c8 + 4];
    for (int np = 0; np < 8; ++np) {
        int node = tile * 16 + np * 2 + h;
        int b = off[node], e = off[node + 1];
        float a[8] = {0.f, 0.f, 0.f, 0.f, 0.f, 0.f, 0.f, 0.f};
        int i = b + q2;
        for (; i + 4 < e; i += 8) {
            unsigned u0 = epack[i];
            unsigned u1 = epack[i + 4];
            uint4 w0 = xw128[(u0 & 0xFFFFu) * 8 + c8];
            uint4 w1 = xw128[(u1 & 0xFFFFu) * 8 + c8];
            float e0 = b2f((unsigned short)(u0 >> 16));
            float e1 = b2f((unsigned short)(u1 >> 16));
            a[0] += e0 * b2f((unsigned short)(w0.x & 0xFFFFu));
            a[1] += e0 * b2f((unsigned short)(w0.x >> 16));
            a[2] += e0 * b2f((unsigned short)(w0.y & 0xFFFFu));
            a[3] += e0 * b2f((unsigned short)(w0.y >> 16));
            a[4] += e0 * b2f((unsigned short)(w0.z & 0xFFFFu));
            a[5] += e0 * b2f((unsigned short)(w0.z >> 16));
            a[6] += e0 * b2f((unsigned short)(w0.w & 0xFFFFu));
            a[7] += e0 * b2f((unsigned short)(w0.w >> 16));
            a[0] += e1 * b2f((unsigned short)(w1.x & 0xFFFFu));
            a[1] += e1 * b2f((unsigned short)(w1.x >> 16));
            a[2] += e1 * b2f((unsigned short)(w1.y & 0xFFFFu));
            a[3] += e1 * b2f((unsigned short)(w1.y >> 16));
            a[4] += e1 * b2f((unsigned short)(w1.z & 0xFFFFu));
            a[5] += e1 * b2f((unsigned short)(w1.z >> 16));
            a[6] += e1 * b2f((unsigned short)(w1.w & 0xFFFFu));
            a[7] += e1 * b2f((unsigned short)(w1.w >> 16));
        }
        if (i < e) {
            unsigned u0 = epack[i];
            uint4 w0 = xw128[(u0 & 0xFFFFu) * 8 + c8];
            float e0 = b2f((unsigned short)(u0 >> 16));
            a[0] += e0 * b2f((unsigned short)(w0.x & 0xFFFFu));
            a[1] += e0 * b2f((unsigned short)(w0.x >> 16));
            a[2] += e0 * b2f((unsigned short)(w0.y & 0xFFFFu));
            a[3] += e0 * b2f((unsigned short)(w0.y >> 16));
            a[4] += e0 * b2f((unsigned short)(w0.z & 0xFFFFu));
            a[5] += e0 * b2f((unsigned short)(w0.z >> 16));
            a[6] += e0 * b2f((unsigned short)(w0.w & 0xFFFFu));
            a[7] += e0 * b2f((unsigned short)(w0.w >> 16));
        }
        #pragma unroll
        for (int j = 0; j < 8; ++j) {
            a[j] += __shfl_xor(a[j], 8);
            a[j] += __shfl_xor(a[j], 16);
        }
        if (q2 == 0) {
            union { uint4 v; unsigned short u[8]; } o;
            o.u[0] = f2b(fmaxf(a[0] + bv0.x, 0.f));
            o.u[1] = f2b(fmaxf(a[1] + bv0.y, 0.f));
            o.u[2] = f2b(fmaxf(a[2] + bv0.z, 0.f));
            o.u[3] = f2b(fmaxf(a[3] + bv0.w, 0.f));
            o.u[4] = f2b(fmaxf(a[4] + bv1.x, 0.f));
            o.u[5] = f2b(fmaxf(a[5] + bv1.y, 0.f));
            o.u[6] = f2b(fmaxf(a[6] + bv1.z, 0.f));
            o.u[7] = f2b(fmaxf(a[7] + bv1.w, 0.f));
            *(uint4*)&aggL[(wv * 16 + np * 2 + h) * 72 + 8 * c8] = o.v;
        }
    }
}

// A-frag for K=144 with agg cols in LDS: 0-63 | 64-127(LDS) | 128-143 -> hb80 64-79
__device__ __forceinline__ bf16x8 afrag144(
    int kb, int arow, int c,
    const unsigned short* __restrict__ hb80, const unsigned short* aggRow) {
    bf16x8 a = {0, 0, 0, 0, 0, 0, 0, 0};
    if (kb < 64)       a = *(const bf16x8*)(hb80 + (size_t)arow * 80 + kb);
    else if (kb < 128) a = *(const bf16x8*)(aggRow + c * 72 + (kb - 64));
    else if (kb < 144) a = *(const bf16x8*)(hb80 + (size_t)arow * 80 + (kb - 64));
    return a;
}

// 5) FUSED agg1 + dense layer-2
__global__ __launch_bounds__(256) void k_fd2(
    const int* __restrict__ off, const unsigned* __restrict__ epack,
    const unsigned short* __restrict__ xwA, const float* __restrict__ bc1,
    const unsigned short* __restrict__ B2,
    const float* __restrict__ b21, const float* __restrict__ b22,
    const float* __restrict__ b23,
    unsigned short* __restrict__ hb80, unsigned short* __restrict__ xwB) {
    __shared__ unsigned short aggL[64 * 72];   // 9216 B
    int t = threadIdx.x;
    int wv = t >> 6, ln = t & 63;
    int tile = blockIdx.x * 4 + wv;
    if (tile >= 3125) return;
    agg_tile(tile, wv, ln, off, epack, xwA, bc1, aggL);

    int c = ln & 15, g = ln >> 4;
    int arow = tile * 16 + c;
    const unsigned short* aggRow = aggL + wv * 16 * 72;
    float bia[4];
    #pragma unroll
    for (int j = 0; j < 4; ++j) bia[j] = b21[j * 16 + c];
    float b8 = b22[c], b9 = b23[c];
    f32x4 acc[10];
    #pragma unroll
    for (int nt = 0; nt < 10; ++nt) acc[nt] = f32x4{0.f, 0.f, 0.f, 0.f};
    const bf16x8* bfrag = (const bf16x8*)(B2 + (size_t)ln * 8);
    #pragma unroll
    for (int ks = 0; ks < 5; ++ks) {
        int kb = ks * 32 + g * 8;
        bf16x8 a = afrag144(kb, arow, c, hb80, aggRow);
        #pragma unroll
        for (int nt = 0; nt < 10; ++nt) {
            bf16x8 b = bfrag[(nt * 5 + ks) * 64];
            acc[nt] = __builtin_amdgcn_mfma_f32_16x16x32_bf16(a, b, acc[nt], 0, 0, 0);
        }
    }
    #pragma unroll
    for (int r = 0; r < 4; ++r) {
        int orow = tile * 16 + g * 4 + r;
        size_t hbase = (size_t)orow * 80;
        #pragma unroll
        for (int nt = 0; nt < 4; ++nt)
            hb80[hbase + nt * 16 + c] = f2b(fmaxf(acc[nt][r] + bia[nt], 0.f));
        #pragma unroll
        for (int nt = 4; nt < 8; ++nt)
            xwB[(size_t)orow * 64 + (nt - 4) * 16 + c] = f2b(acc[nt][r]);
        float p = fmaxf(acc[8][r] + b8, 0.f) * fmaxf(acc[9][r] + b9, 0.f);
        hb80[hbase + 64 + c] = f2b(p);
    }
}

// 6) FUSED agg2 + classifier + log_softmax
__global__ __launch_bounds__(256) void k_fcls(
    const int* __restrict__ off, const unsigned* __restrict__ epack,
    const unsigned short* __restrict__ xwB, const float* __restrict__ bc2,
    const unsigned short* __restrict__ hb80,
    const unsigned short* __restrict__ Bc, const float* __restrict__ bfb,
    float* __restrict__ out) {
    __shared__ unsigned short aggL[64 * 72];
    int t = threadIdx.x;
    int wv = t >> 6, ln = t & 63;
    int tile = blockIdx.x * 4 + wv;
    if (tile >= 3125) return;
    agg_tile(tile, wv, ln, off, epack, xwB, bc2, aggL);

    int c = ln & 15, g = ln >> 4;
    int arow = tile * 16 + c;
    const unsigned short* aggRow = aggL + wv * 16 * 72;
    float bia[8];
    #pragma unroll
    for (int j = 0; j < 8; ++j) bia[j] = bfb[j * 16 + c];
    f32x4 acc[8];
    #pragma unroll
    for (int nt = 0; nt < 8; ++nt) acc[nt] = f32x4{0.f, 0.f, 0.f, 0.f};
    const bf16x8* bfrag = (const bf16x8*)(Bc + (size_t)ln * 8);
    #pragma unroll
    for (int ks = 0; ks < 5; ++ks) {
        int kb = ks * 32 + g * 8;
        bf16x8 a = afrag144(kb, arow, c, hb80, aggRow);
        #pragma unroll
        for (int nt = 0; nt < 8; ++nt) {
            bf16x8 b = bfrag[(nt * 5 + ks) * 64];
            acc[nt] = __builtin_amdgcn_mfma_f32_16x16x32_bf16(a, b, acc[nt], 0, 0, 0);
        }
    }
    #pragma unroll
    for (int r = 0; r < 4; ++r) {
        float lg[8];
        #pragma unroll
        for (int nt = 0; nt < 8; ++nt) lg[nt] = acc[nt][r] + bia[nt];
        float m = lg[0];
        #pragma unroll
        for (int nt = 1; nt < 8; ++nt) m = fmaxf(m, lg[nt]);
        #pragma unroll
        for (int o = 1; o < 16; o <<= 1) m = fmaxf(m, __shfl_xor(m, o));
        float s = 0.f;
        #pragma unroll
        for (int nt = 0; nt < 8; ++nt) s += __expf(lg[nt] - m);
        #pragma unroll
        for (int o = 1; o < 16; o <<= 1) s += __shfl_xor(s, o);
        float ls = __logf(s) + m;
        int orow = tile * 16 + g * 4 + r;
        #pragma unroll
        for (int nt = 0; nt < 8; ++nt)
            out[(size_t)orow * 128 + nt * 16 + c] = lg[nt] - ls;
    }
}

// ---------------- launch ----------------

extern "C" void kernel_launch(void* const* d_in, const int* in_sizes, int n_in,
                              void* d_out, int out_size, void* d_ws, size_t ws_size,
                              hipStream_t stream) {
    const float* x   = (const float*)d_in[0];
    const int*   ei  = (const int*)d_in[1];
    const float* ea  = (const float*)d_in[2];
    const float* Wc1 = (const float*)d_in[3];
    const float* bc1 = (const float*)d_in[4];
    const float* Wc2 = (const float*)d_in[5];
    const float* bc2 = (const float*)d_in[6];
    const float* W11 = (const float*)d_in[7];
    const float* b11 = (const float*)d_in[8];
    const float* W12 = (const float*)d_in[9];
    const float* b12 = (const float*)d_in[10];
    const float* W13 = (const float*)d_in[11];
    const float* b13 = (const float*)d_in[12];
    const float* W21 = (const float*)d_in[13];
    const float* b21 = (const float*)d_in[14];
    const float* W22 = (const float*)d_in[15];
    const float* b22 = (const float*)d_in[16];
    const float* W23 = (const float*)d_in[17];
    const float* b23 = (const float*)d_in[18];
    const float* Wf  = (const float*)d_in[19];
    const float* bfb = (const float*)d_in[20];

    const int* esrc = ei;
    const int* edst = ei + N_EDGES;

    // layer-1 xw lives in d_out (6.4 MB; dead before k_fcls writes out)
    unsigned short* xwA = (unsigned short*)d_out;

    // ws carve (~18.1 MB; ebuf reused as layer-2 xw after k_sub):
    int*            off   = (int*)d_ws;                          // 50008
    int*            cntM  = off + 50008;                         // 38416
    int*            btot  = cntM + NBLK * NBUK;                  // 200
    uint2*          ebuf  = (uint2*)(btot + 200);                // E*8B (== xwB later)
    unsigned*       epack = (unsigned*)(ebuf + N_EDGES);         // E*4B
    unsigned short* hb80  = (unsigned short*)(epack + N_EDGES);  // N*80 bf16
    unsigned short* B1    = hb80 + (size_t)N_NODES * 80;         // 10240
    unsigned short* B2    = B1 + 10240;                          // 25600
    unsigned short* Bc    = B2 + 25600;                          // 20480
    unsigned short* xwB   = (unsigned short*)ebuf;               // N*64 bf16 (6.4MB == ebuf)

    k_cnt  <<<NBLK + PREP_NB, 256, 0, stream>>>(edst, cntM,
        W11, Wc1, W12, W13, W21, Wc2, W22, W23, Wf, B1, B2, Bc);
    k_colA <<<49, 256, 0, stream>>>(cntM, btot);
    k_bd1  <<<NBLK + GD, 256, 0, stream>>>(esrc, edst, ea, cntM, btot, ebuf,
        x, B1, b11, b12, b13, hb80, xwA);
    k_sub  <<<NBUK, 256, 0, stream>>>(ebuf, btot, epack, off);
    k_fd2  <<<GD, 256, 0, stream>>>(off, epack, xwA, bc1, B2, b21, b22, b23, hb80, xwB);
    k_fcls <<<GD, 256, 0, stream>>>(off, epack, xwB, bc2, hb80, Bc, bfb, (float*)d_out);
}

// Round 16
// 115.026 us; speedup vs baseline: 1.3035x; 1.3035x over previous
//
#include <hip/hip_runtime.h>
#include <hip/hip_bf16.h>

#define N_NODES 50000
#define N_EDGES 800000
#define NBUK 196          // buckets of 256 dst nodes
#define NBLK 196          // edge-chunk blocks: 196*4096 >= E
#define EPB  4096
#define PREP_NB 220
#define GD 782            // 782*4 wave-tiles >= 3125
#define SUBCAP 4608

typedef __attribute__((ext_vector_type(8))) short bf16x8;
typedef __attribute__((ext_vector_type(4))) float f32x4;

__device__ __forceinline__ unsigned short f2b(float f) {
    unsigned u = __float_as_uint(f);
    return (unsigned short)((u + 0x7FFF + ((u >> 16) & 1)) >> 16);
}
__device__ __forceinline__ float b2f(unsigned short b) {
    return __uint_as_float(((unsigned)b) << 16);
}

// in-block exclusive scan of btot[NBUK] -> seb[NBUK+1] (seb/wsum in LDS)
__device__ __forceinline__ void scan_btot(const int* __restrict__ btot,
                                          int* seb, int* wsum, int t) {
    int v = (t < NBUK) ? btot[t] : 0;
    int lane = t & 63, wid = t >> 6;
    int incl = v;
    #pragma unroll
    for (int d = 1; d < 64; d <<= 1) {
        int u = __shfl_up(incl, d);
        if (lane >= d) incl += u;
    }
    if (lane == 63) wsum[wid] = incl;
    __syncthreads();
    int woff = 0;
    for (int w = 0; w < wid; ++w) woff += wsum[w];
    if (t < NBUK) seb[t] = incl - v + woff;
    if (t == 255) seb[NBUK] = incl + woff;    // == N_EDGES
    __syncthreads();
}

// ---------------- MFMA dense body (round-14 proven) ----------------
// Wave owns one 16-row M-tile, 10 n-tiles of 16 cols. B-frags from pre-built
// global layout (L2-broadcast). D-frag (verified m89/m91): col=lane&15,
// row=(lane>>4)*4+reg.

template<int KREAL>
__device__ __forceinline__ void dense_body(
    int tile, int ln,
    const float* __restrict__ xf, const unsigned short* __restrict__ hb_in,
    const unsigned short* __restrict__ Bw,
    const float* __restrict__ b1, const float* __restrict__ b2,
    const float* __restrict__ b3,
    unsigned short* __restrict__ hb, unsigned short* __restrict__ xwb) {
    constexpr int KS = (KREAL + 31) / 32;      // 2 or 5
    if (tile >= 3125) return;                  // 50000 = 3125*16 exact
    int c = ln & 15, g = ln >> 4;
    int arow = tile * 16 + c;
    float bia[4];
    #pragma unroll
    for (int j = 0; j < 4; ++j) bia[j] = b1[j * 16 + c];
    float b8 = b2[c], b9 = b3[c];

    f32x4 acc[10];
    #pragma unroll
    for (int nt = 0; nt < 10; ++nt) acc[nt] = f32x4{0.f, 0.f, 0.f, 0.f};

    const bf16x8* bfrag = (const bf16x8*)(Bw + (size_t)ln * 8);
    #pragma unroll
    for (int ks = 0; ks < KS; ++ks) {
        int kb = ks * 32 + g * 8;
        bf16x8 a = {0, 0, 0, 0, 0, 0, 0, 0};
        if constexpr (KREAL == 64) {
            const float* rp = xf + (size_t)arow * 64 + kb;
            float4 q0 = *(const float4*)rp;
            float4 q1 = *(const float4*)(rp + 4);
            union { bf16x8 v; unsigned short u[8]; } af;
            af.u[0] = f2b(q0.x); af.u[1] = f2b(q0.y); af.u[2] = f2b(q0.z); af.u[3] = f2b(q0.w);
            af.u[4] = f2b(q1.x); af.u[5] = f2b(q1.y); af.u[6] = f2b(q1.z); af.u[7] = f2b(q1.w);
            a = af.v;
        } else {
            if (kb < 144) a = *(const bf16x8*)(hb_in + (size_t)arow * 144 + kb);
        }
        #pragma unroll
        for (int nt = 0; nt < 10; ++nt) {
            bf16x8 b = bfrag[(nt * KS + ks) * 64];
            acc[nt] = __builtin_amdgcn_mfma_f32_16x16x32_bf16(a, b, acc[nt], 0, 0, 0);
        }
    }
    #pragma unroll
    for (int r = 0; r < 4; ++r) {
        int orow = tile * 16 + g * 4 + r;
        size_t hbase = (size_t)orow * 144;
        #pragma unroll
        for (int nt = 0; nt < 4; ++nt)
            hb[hbase + nt * 16 + c] = f2b(fmaxf(acc[nt][r] + bia[nt], 0.f));
        #pragma unroll
        for (int nt = 4; nt < 8; ++nt)
            xwb[(size_t)orow * 64 + (nt - 4) * 16 + c] = f2b(acc[nt][r]);
        float p = fmaxf(acc[8][r] + b8, 0.f) * fmaxf(acc[9][r] + b9, 0.f);
        hb[hbase + 128 + c] = f2b(p);
    }
}

// ---------------- CSR build (two-level bucket sort) ----------------

// 1) per-(block,bucket) counts TRANSPOSED; blocks >= NBLK do weight prep
__global__ __launch_bounds__(256) void k_cnt(
    const int* __restrict__ dst, int* __restrict__ cntM,
    const float* __restrict__ W11, const float* __restrict__ Wc1,
    const float* __restrict__ W12, const float* __restrict__ W13,
    const float* __restrict__ W21, const float* __restrict__ Wc2,
    const float* __restrict__ W22, const float* __restrict__ W23,
    const float* __restrict__ Wf,
    unsigned short* __restrict__ B1, unsigned short* __restrict__ B2,
    unsigned short* __restrict__ Bc) {
    int t = threadIdx.x, blk = blockIdx.x;
    if (blk >= NBLK) {
        // frag layout: B[((nt*KS+ks)*64+lane)*8+i] = W(k=ks*32+(lane>>4)*8+i, col=nt*16+(lane&15))
        int idx = (blk - NBLK) * 256 + t;
        if (idx < 10240) {                       // B1: KS=2, K=64, 160 cols
            int i = idx & 7, l = (idx >> 3) & 63, ks = (idx >> 9) & 1, nt = idx >> 10;
            int k = ks * 32 + ((l >> 4) << 3) + i;
            int col = nt * 16 + (l & 15);
            float w = (col < 64) ? W11[k * 64 + col]
                    : (col < 128) ? Wc1[k * 64 + col - 64]
                    : (col < 144) ? W12[k * 16 + col - 128]
                                  : W13[k * 16 + col - 144];
            B1[idx] = f2b(w);
        } else if (idx < 10240 + 25600) {        // B2: KS=5, K=144, 160 cols
            int j = idx - 10240;
            int i = j & 7, l = (j >> 3) & 63;
            int ks = (j >> 9) % 5, nt = j / 2560;
            int k = ks * 32 + ((l >> 4) << 3) + i;
            int col = nt * 16 + (l & 15);
            float w = 0.f;
            if (k < 144)
                w = (col < 64) ? W21[k * 64 + col]
                  : (col < 128) ? Wc2[k * 64 + col - 64]
                  : (col < 144) ? W22[k * 16 + col - 128]
                                : W23[k * 16 + col - 144];
            B2[j] = f2b(w);
        } else if (idx < 10240 + 25600 + 20480) { // Bc: KS=5, K=144, 128 cols
            int j = idx - 10240 - 25600;
            int i = j & 7, l = (j >> 3) & 63;
            int ks = (j >> 9) % 5, nt = j / 2560;
            int k = ks * 32 + ((l >> 4) << 3) + i;
            int col = nt * 16 + (l & 15);
            Bc[j] = (k < 144) ? f2b(Wf[k * 128 + col]) : (unsigned short)0;
        }
        return;
    }
    __shared__ int cl[NBUK];
    for (int i = t; i < NBUK; i += 256) cl[i] = 0;
    __syncthreads();
    int e0 = blk * EPB;
    #pragma unroll
    for (int r = 0; r < EPB / 256; ++r) {
        int e = e0 + r * 256 + t;
        if (e < N_EDGES) atomicAdd(&cl[dst[e] >> 8], 1);
    }
    __syncthreads();
    for (int i = t; i < NBUK; i += 256) cntM[i * NBLK + blk] = cl[i];
}

// 2) per-bucket scan over blocks (wave per bucket); bucket totals -> btot
__global__ __launch_bounds__(256) void k_colA(int* __restrict__ cntM,
                                              int* __restrict__ btot) {
    int t = threadIdx.x;
    int k = blockIdx.x * 4 + (t >> 6);
    int lane = t & 63;
    int* row = cntM + k * NBLK;
    int4 v = {0, 0, 0, 0};
    if (lane < 49) v = *(const int4*)&row[lane * 4];
    int s = v.x + v.y + v.z + v.w;
    int incl = s;
    #pragma unroll
    for (int d = 1; d < 64; d <<= 1) {
        int u = __shfl_up(incl, d);
        if (lane >= d) incl += u;
    }
    int excl = incl - s;
    if (lane < 49) {
        int4 o;
        o.x = excl;
        o.y = excl + v.x;
        o.z = excl + v.x + v.y;
        o.w = excl + v.x + v.y + v.z;
        *(int4*)&row[lane * 4] = o;
    }
    if (lane == 63) btot[k] = incl;
}

// 3) MERGED: blocks [0,NBLK) bucketize (ebase derived in-block from btot);
//    blocks [NBLK,NBLK+GD) run dense layer-1.
__global__ __launch_bounds__(256) void k_bd1(
    const int* __restrict__ src, const int* __restrict__ dst,
    const float* __restrict__ ea, const int* __restrict__ cntM,
    const int* __restrict__ btot, uint2* __restrict__ ebuf,
    const float* __restrict__ xf, const unsigned short* __restrict__ B1,
    const float* __restrict__ b11, const float* __restrict__ b12,
    const float* __restrict__ b13,
    unsigned short* __restrict__ hb, unsigned short* __restrict__ xwb) {
    int t = threadIdx.x, blk = blockIdx.x;
    if (blk >= NBLK) {
        int tile = (blk - NBLK) * 4 + (t >> 6);
        dense_body<64>(tile, t & 63, xf, nullptr, B1, b11, b12, b13, hb, xwb);
        return;
    }
    __shared__ int seb[NBUK + 1];
    __shared__ int wsum[4];
    __shared__ int base[NBUK];
    __shared__ int run[NBUK];
    scan_btot(btot, seb, wsum, t);
    if (t < NBUK) { base[t] = seb[t] + cntM[t * NBLK + blk]; run[t] = 0; }
    __syncthreads();
    int e0 = blk * EPB;
    #pragma unroll
    for (int r = 0; r < EPB / 256; ++r) {
        int e = e0 + r * 256 + t;
        if (e < N_EDGES) {
            int d = dst[e];
            int bk = d >> 8;
            int pos = atomicAdd(&run[bk], 1);
            ebuf[base[bk] + pos] =
                make_uint2((((unsigned)f2b(ea[e])) << 16) | (unsigned)src[e],
                           (unsigned)(d & 255));
        }
    }
}

// 4) per-bucket: LDS-cached edges; deg+scan -> off[]; dst-sorted epack
__global__ __launch_bounds__(256) void k_sub(
    const uint2* __restrict__ ebuf, const int* __restrict__ btot,
    unsigned* __restrict__ epack, int* __restrict__ off) {
    __shared__ uint2 ebl[SUBCAP];
    __shared__ int seb[NBUK + 1];
    __shared__ int deg[256], lofs[256], cnt[256];
    __shared__ int wsum[4];
    int t = threadIdx.x, b = blockIdx.x;
    scan_btot(btot, seb, wsum, t);
    deg[t] = 0; cnt[t] = 0;
    __syncthreads();
    int s = seb[b], e = seb[b + 1];
    int n = e - s;
    bool lds = (n <= SUBCAP);
    if (lds) {
        for (int i = t; i < n; i += 256) {
            uint2 u = ebuf[s + i];
            ebl[i] = u;
            atomicAdd(&deg[u.y], 1);
        }
    } else {
        for (int i = s + t; i < e; i += 256) atomicAdd(&deg[ebuf[i].y], 1);
    }
    __syncthreads();
    int v = deg[t];
    int lane = t & 63, wid = t >> 6;
    int incl = v;
    #pragma unroll
    for (int d = 1; d < 64; d <<= 1) {
        int u = __shfl_up(incl, d);
        if (lane >= d) incl += u;
    }
    if (lane == 63) wsum[wid] = incl;
    __syncthreads();
    int woff = 0;
    for (int w = 0; w < wid; ++w) woff += wsum[w];
    lofs[t] = incl - v + woff;
    __syncthreads();
    int gd = b * 256 + t;
    if (gd < N_NODES) off[gd] = s + lofs[t];
    if (b == NBUK - 1 && t == 0) off[N_NODES] = N_EDGES;
    if (lds) {
        for (int i = t; i < n; i += 256) {
            uint2 u = ebl[i];
            int pos = atomicAdd(&cnt[u.y], 1);
            epack[s + lofs[u.y] + pos] = u.x;
        }
    } else {
        for (int i = s + t; i < e; i += 256) {
            uint2 u = ebuf[i];
            int pos = atomicAdd(&cnt[u.y], 1);
            epack[s + lofs[u.y] + pos] = u.x;
        }
    }
}

// ---------------- dense layer-2 (standalone; depends on agg1) ----------------

__global__ __launch_bounds__(256) void k_dense2(
    const unsigned short* __restrict__ hb_in, const unsigned short* __restrict__ B2,
    const float* __restrict__ b21, const float* __restrict__ b22,
    const float* __restrict__ b23,
    unsigned short* __restrict__ hb, unsigned short* __restrict__ xwb) {
    int t = threadIdx.x;
    int tile = blockIdx.x * 4 + (t >> 6);
    dense_body<144>(tile, t & 63, nullptr, hb_in, B2, b21, b22, b23, hb, xwb);
}

// ---------------- aggregation: wave per dst node, 8 edges/iter, 2x unroll ----
// (round-14 proven: 12500 blocks, 1 node/wave, 16 gathers in flight)

__global__ __launch_bounds__(256) void k_agg(
    const unsigned short* __restrict__ xwb, const int* __restrict__ off,
    const unsigned* __restrict__ epack,
    const float* __restrict__ bc, unsigned short* __restrict__ hb) {
    int node = blockIdx.x * 4 + (threadIdx.x >> 6);
    int lane = threadIdx.x & 63;
    if (node >= N_NODES) return;
    const uint4* xw128 = (const uint4*)xwb;   // 8 uint4 per node row
    int b = off[node], e = off[node + 1];
    int q = lane >> 3, c = lane & 7;
    float a[8] = {0.f, 0.f, 0.f, 0.f, 0.f, 0.f, 0.f, 0.f};
    int i = b + q;
    for (; i + 8 < e; i += 16) {
        unsigned u0 = epack[i];
        unsigned u1 = epack[i + 8];
        uint4 w0 = xw128[(u0 & 0xFFFFu) * 8 + c];
        uint4 w1 = xw128[(u1 & 0xFFFFu) * 8 + c];
        float e0 = b2f((unsigned short)(u0 >> 16));
        float e1 = b2f((unsigned short)(u1 >> 16));
        a[0] += e0 * b2f((unsigned short)(w0.x & 0xFFFFu));
        a[1] += e0 * b2f((unsigned short)(w0.x >> 16));
        a[2] += e0 * b2f((unsigned short)(w0.y & 0xFFFFu));
        a[3] += e0 * b2f((unsigned short)(w0.y >> 16));
        a[4] += e0 * b2f((unsigned short)(w0.z & 0xFFFFu));
        a[5] += e0 * b2f((unsigned short)(w0.z >> 16));
        a[6] += e0 * b2f((unsigned short)(w0.w & 0xFFFFu));
        a[7] += e0 * b2f((unsigned short)(w0.w >> 16));
        a[0] += e1 * b2f((unsigned short)(w1.x & 0xFFFFu));
        a[1] += e1 * b2f((unsigned short)(w1.x >> 16));
        a[2] += e1 * b2f((unsigned short)(w1.y & 0xFFFFu));
        a[3] += e1 * b2f((unsigned short)(w1.y >> 16));
        a[4] += e1 * b2f((unsigned short)(w1.z & 0xFFFFu));
        a[5] += e1 * b2f((unsigned short)(w1.z >> 16));
        a[6] += e1 * b2f((unsigned short)(w1.w & 0xFFFFu));
        a[7] += e1 * b2f((unsigned short)(w1.w >> 16));
    }
    if (i < e) {
        unsigned u0 = epack[i];
        uint4 w0 = xw128[(u0 & 0xFFFFu) * 8 + c];
        float e0 = b2f((unsigned short)(u0 >> 16));
        a[0] += e0 * b2f((unsigned short)(w0.x & 0xFFFFu));
        a[1] += e0 * b2f((unsigned short)(w0.x >> 16));
        a[2] += e0 * b2f((unsigned short)(w0.y & 0xFFFFu));
        a[3] += e0 * b2f((unsigned short)(w0.y >> 16));
        a[4] += e0 * b2f((unsigned short)(w0.z & 0xFFFFu));
        a[5] += e0 * b2f((unsigned short)(w0.z >> 16));
        a[6] += e0 * b2f((unsigned short)(w0.w & 0xFFFFu));
        a[7] += e0 * b2f((unsigned short)(w0.w >> 16));
    }
    #pragma unroll
    for (int j = 0; j < 8; ++j) {
        a[j] += __shfl_xor(a[j], 8);
        a[j] += __shfl_xor(a[j], 16);
        a[j] += __shfl_xor(a[j], 32);
    }
    if (q == 0) {
        int f0 = 8 * c;
        float4 bv0 = *(const float4*)&bc[f0];
        float4 bv1 = *(const float4*)&bc[f0 + 4];
        union { uint4 v; unsigned short u[8]; } o;
        o.u[0] = f2b(fmaxf(a[0] + bv0.x, 0.f));
        o.u[1] = f2b(fmaxf(a[1] + bv0.y, 0.f));
        o.u[2] = f2b(fmaxf(a[2] + bv0.z, 0.f));
        o.u[3] = f2b(fmaxf(a[3] + bv0.w, 0.f));
        o.u[4] = f2b(fmaxf(a[4] + bv1.x, 0.f));
        o.u[5] = f2b(fmaxf(a[5] + bv1.y, 0.f));
        o.u[6] = f2b(fmaxf(a[6] + bv1.z, 0.f));
        o.u[7] = f2b(fmaxf(a[7] + bv1.w, 0.f));
        *(uint4*)&hb[(size_t)node * 144 + 64 + f0] = o.v;
    }
}

// ---------------- classifier MFMA GEMM + log_softmax (no LDS) ----------------

__global__ __launch_bounds__(256) void k_cls(
    const unsigned short* __restrict__ hb,
    const unsigned short* __restrict__ Bw,
    const float* __restrict__ bfb,
    float* __restrict__ out) {
    int t = threadIdx.x;
    int wv = t >> 6, ln = t & 63;
    int tile = blockIdx.x * 4 + wv;
    if (tile >= 3125) return;
    int c = ln & 15, g = ln >> 4;
    int arow = tile * 16 + c;
    float bia[8];
    #pragma unroll
    for (int j = 0; j < 8; ++j) bia[j] = bfb[j * 16 + c];
    f32x4 acc[8];
    #pragma unroll
    for (int nt = 0; nt < 8; ++nt) acc[nt] = f32x4{0.f, 0.f, 0.f, 0.f};

    const bf16x8* bfrag = (const bf16x8*)(Bw + (size_t)ln * 8);
    #pragma unroll
    for (int ks = 0; ks < 5; ++ks) {
        int kb = ks * 32 + g * 8;
        bf16x8 a = {0, 0, 0, 0, 0, 0, 0, 0};
        if (kb < 144) a = *(const bf16x8*)(hb + (size_t)arow * 144 + kb);
        #pragma unroll
        for (int nt = 0; nt < 8; ++nt) {
            bf16x8 b = bfrag[(nt * 5 + ks) * 64];
            acc[nt] = __builtin_amdgcn_mfma_f32_16x16x32_bf16(a, b, acc[nt], 0, 0, 0);
        }
    }
    #pragma unroll
    for (int r = 0; r < 4; ++r) {
        float lg[8];
        #pragma unroll
        for (int nt = 0; nt < 8; ++nt) lg[nt] = acc[nt][r] + bia[nt];
        float m = lg[0];
        #pragma unroll
        for (int nt = 1; nt < 8; ++nt) m = fmaxf(m, lg[nt]);
        #pragma unroll
        for (int o = 1; o < 16; o <<= 1) m = fmaxf(m, __shfl_xor(m, o));
        float s = 0.f;
        #pragma unroll
        for (int nt = 0; nt < 8; ++nt) s += __expf(lg[nt] - m);
        #pragma unroll
        for (int o = 1; o < 16; o <<= 1) s += __shfl_xor(s, o);
        float ls = __logf(s) + m;
        int orow = tile * 16 + g * 4 + r;
        #pragma unroll
        for (int nt = 0; nt < 8; ++nt)
            out[(size_t)orow * 128 + nt * 16 + c] = lg[nt] - ls;
    }
}

// ---------------- launch ----------------

extern "C" void kernel_launch(void* const* d_in, const int* in_sizes, int n_in,
                              void* d_out, int out_size, void* d_ws, size_t ws_size,
                              hipStream_t stream) {
    const float* x   = (const float*)d_in[0];
    const int*   ei  = (const int*)d_in[1];
    const float* ea  = (const float*)d_in[2];
    const float* Wc1 = (const float*)d_in[3];
    const float* bc1 = (const float*)d_in[4];
    const float* Wc2 = (const float*)d_in[5];
    const float* bc2 = (const float*)d_in[6];
    const float* W11 = (const float*)d_in[7];
    const float* b11 = (const float*)d_in[8];
    const float* W12 = (const float*)d_in[9];
    const float* b12 = (const float*)d_in[10];
    const float* W13 = (const float*)d_in[11];
    const float* b13 = (const float*)d_in[12];
    const float* W21 = (const float*)d_in[13];
    const float* b21 = (const float*)d_in[14];
    const float* W22 = (const float*)d_in[15];
    const float* b22 = (const float*)d_in[16];
    const float* W23 = (const float*)d_in[17];
    const float* b23 = (const float*)d_in[18];
    const float* Wf  = (const float*)d_in[19];
    const float* bfb = (const float*)d_in[20];

    const int* esrc = ei;
    const int* edst = ei + N_EDGES;

    // xw bf16 [N][64] lives in d_out (6.4 MB; dead before k_cls writes out).
    unsigned short* xwb = (unsigned short*)d_out;

    // workspace carve (16B-alignment maintained for ebuf/hb/B*):
    int*            off   = (int*)d_ws;                          // 50008 ints
    int*            cntM  = off + 50008;                         // 38416 ints
    int*            btot  = cntM + NBLK * NBUK;                  // 196 (+pad 4)
    uint2*          ebuf  = (uint2*)(btot + 200);                // E * 8B
    unsigned*       epack = (unsigned*)(ebuf + N_EDGES);         // E * 4B
    unsigned short* hb    = (unsigned short*)(epack + N_EDGES);  // N*144 bf16
    unsigned short* B1    = hb + (size_t)N_NODES * 144;          // 10240
    unsigned short* B2    = B1 + 10240;                          // 25600
    unsigned short* Bc    = B2 + 25600;                          // 20480

    k_cnt    <<<NBLK + PREP_NB, 256, 0, stream>>>(edst, cntM,
        W11, Wc1, W12, W13, W21, Wc2, W22, W23, Wf, B1, B2, Bc);
    k_colA   <<<49, 256, 0, stream>>>(cntM, btot);
    k_bd1    <<<NBLK + GD, 256, 0, stream>>>(esrc, edst, ea, cntM, btot, ebuf,
        x, B1, b11, b12, b13, hb, xwb);
    k_sub    <<<NBUK, 256, 0, stream>>>(ebuf, btot, epack, off);

    k_agg    <<<(N_NODES + 3) / 4, 256, 0, stream>>>(xwb, off, epack, bc1, hb);
    k_dense2 <<<GD, 256, 0, stream>>>(hb, B2, b21, b22, b23, hb, xwb);
    k_agg    <<<(N_NODES + 3) / 4, 256, 0, stream>>>(xwb, off, epack, bc2, hb);
    k_cls    <<<GD, 256, 0, stream>>>(hb, Bc, bfb, (float*)d_out);
}